// Round 1
// baseline (309.314 us; speedup 1.0000x reference)
//
#include <hip/hip_runtime.h>

// EVDLoRA loss: a[N=2048, R=4, D=256] f32 -> scalar f32.
// Flatten A = [P=8192][256].  S = A A^T.  For each (i,k,j): max over l of S,
// dp = exp(s - max).  i!=k: sum fmax(dp^2,1e-8)*C_NEG ; i==k: -C_POS*sum_{l!=j} dp.
// (k==i clamp-square terms cancel exactly against diag_sq in the reference.)

#define PD   8192
#define DDIM 256
#define BM   128
#define KS   16
#define LDP  132   // padded K-major row pitch (floats), 4-aligned for float4

__device__ __forceinline__ float groupNeg(float s0, float s1, float s2, float s3) {
    float mmax = fmaxf(fmaxf(s0, s1), fmaxf(s2, s3));
    float d0 = __expf(s0 - mmax), d1 = __expf(s1 - mmax);
    float d2 = __expf(s2 - mmax), d3 = __expf(s3 - mmax);
    return fmaxf(d0 * d0, 1e-8f) + fmaxf(d1 * d1, 1e-8f) +
           fmaxf(d2 * d2, 1e-8f) + fmaxf(d3 * d3, 1e-8f);
}

__global__ __launch_bounds__(256, 2)
void evd_main(const float* __restrict__ A, float* __restrict__ out)
{
    const int bi = blockIdx.y, bk = blockIdx.x;
    if (bk < bi) return;   // upper triangle only (symmetry)

    __shared__ float As[KS][LDP];
    __shared__ float Bs[KS][LDP];
    __shared__ float wsum[4];

    const int tid = threadIdx.x;
    const int tx = tid & 15, ty = tid >> 4;
    const int row0 = bi * BM, col0 = bk * BM;

    float acc[8][8];
#pragma unroll
    for (int m = 0; m < 8; ++m)
#pragma unroll
        for (int n = 0; n < 8; ++n) acc[m][n] = 0.f;

    const float* __restrict__ Arow = A + (size_t)row0 * DDIM;
    const float* __restrict__ Brow = A + (size_t)col0 * DDIM;

    for (int kc = 0; kc < DDIM; kc += KS) {
        // stage 128 rows x 16 cols of each operand, transposed to K-major LDS
#pragma unroll
        for (int u = 0; u < 2; ++u) {
            const int e = tid + u * 256;       // 512 float4 loads per tile
            const int r = e >> 2, g = e & 3;   // r: row 0..127, g: float4 within 16 cols
            const float4 va = *reinterpret_cast<const float4*>(Arow + r * DDIM + kc + g * 4);
            As[g * 4 + 0][r] = va.x; As[g * 4 + 1][r] = va.y;
            As[g * 4 + 2][r] = va.z; As[g * 4 + 3][r] = va.w;
            const float4 vb = *reinterpret_cast<const float4*>(Brow + r * DDIM + kc + g * 4);
            Bs[g * 4 + 0][r] = vb.x; Bs[g * 4 + 1][r] = vb.y;
            Bs[g * 4 + 2][r] = vb.z; Bs[g * 4 + 3][r] = vb.w;
        }
        __syncthreads();
#pragma unroll
        for (int kk = 0; kk < KS; ++kk) {
            float a[8], b[8];
            *(float4*)&a[0] = *(const float4*)&As[kk][ty * 8];
            *(float4*)&a[4] = *(const float4*)&As[kk][ty * 8 + 4];
            *(float4*)&b[0] = *(const float4*)&Bs[kk][tx * 8];
            *(float4*)&b[4] = *(const float4*)&Bs[kk][tx * 8 + 4];
#pragma unroll
            for (int m = 0; m < 8; ++m)
#pragma unroll
                for (int n = 0; n < 8; ++n)
                    acc[m][n] = fmaf(a[m], b[n], acc[m][n]);
        }
        __syncthreads();
    }

    const float C_NEG = 1.0f / (2048.0f * 2047.0f * 16.0f);
    const float C_POS = 2.0f / (2048.0f * 12.0f);
    float contrib = 0.f;

    // row-side epilogue: i from row tile, k from col tile
#pragma unroll
    for (int m = 0; m < 8; ++m) {
        const int p = row0 + ty * 8 + m;
        const int i = p >> 2, j = p & 3;
#pragma unroll
        for (int kg = 0; kg < 2; ++kg) {
            const int k = (col0 + tx * 8 + kg * 4) >> 2;
            const float s0 = acc[m][kg * 4 + 0], s1 = acc[m][kg * 4 + 1];
            const float s2 = acc[m][kg * 4 + 2], s3 = acc[m][kg * 4 + 3];
            if (i != k) {
                contrib += C_NEG * groupNeg(s0, s1, s2, s3);
            } else {
                const float mmax = fmaxf(fmaxf(s0, s1), fmaxf(s2, s3));
                const float d0 = __expf(s0 - mmax), d1 = __expf(s1 - mmax);
                const float d2 = __expf(s2 - mmax), d3 = __expf(s3 - mmax);
                const float dj = (j == 0) ? d0 : (j == 1) ? d1 : (j == 2) ? d2 : d3;
                contrib -= C_POS * (d0 + d1 + d2 + d3 - dj);
            }
        }
    }

    // transposed epilogue for off-diagonal tiles: i' from col tile, k' from row tile.
    // sim[i',k',j',l'] = S[k'*4+l'][i'*4+j'] -> max over l' = max over 4 rows (one mg group).
    if (bi != bk) {
#pragma unroll
        for (int n = 0; n < 8; ++n) {
#pragma unroll
            for (int mg = 0; mg < 2; ++mg) {
                contrib += C_NEG * groupNeg(acc[mg * 4 + 0][n], acc[mg * 4 + 1][n],
                                            acc[mg * 4 + 2][n], acc[mg * 4 + 3][n]);
            }
        }
    }

    // block reduction -> one atomic per block
#pragma unroll
    for (int off = 32; off; off >>= 1) contrib += __shfl_down(contrib, off);
    if ((tid & 63) == 0) wsum[tid >> 6] = contrib;
    __syncthreads();
    if (tid == 0) atomicAdd(out, wsum[0] + wsum[1] + wsum[2] + wsum[3]);
}

extern "C" void kernel_launch(void* const* d_in, const int* in_sizes, int n_in,
                              void* d_out, int out_size, void* d_ws, size_t ws_size,
                              hipStream_t stream) {
    const float* A = (const float*)d_in[0];
    float* out = (float*)d_out;
    hipMemsetAsync(out, 0, sizeof(float), stream);
    dim3 grid(PD / BM, PD / BM);   // 64 x 64, lower triangle early-exits
    evd_main<<<grid, 256, 0, stream>>>(A, out);
}

// Round 2
// 133.188 us; speedup vs baseline: 2.3224x; 2.3224x over previous
//
#include <hip/hip_runtime.h>

// EVDLoRA loss: a[2048,4,256] f32 -> scalar.
// A = [8192][256] f32. Split a = hi + lo (bf16 each), W = [Hi | Lo] : [8192][512] bf16.
// S = A A^T ~= W W^T (exact to ~2^-17 rel), computed with bf16 MFMA, K=512.
// Epilogue fused: per (i,k,j): max over l (4 cols), dp=exp(s-max);
//   i!=k: += fmax(dp^2,1e-8)*C_NEG ; i==k: -= C_POS * sum_{l!=j} dp.
// (k==i clamp-square terms cancel exactly against diag_sq in the reference.)
// Upper-triangle tiles only; off-diag tiles do both orientations.

#define PD   8192
#define DDIM 256
#define KB   512
#define BM   128
#define BK   32

typedef __bf16 bf16x8 __attribute__((ext_vector_type(8)));
typedef __bf16 bf16x4 __attribute__((ext_vector_type(4)));
typedef float f32x4 __attribute__((ext_vector_type(4)));

__device__ __forceinline__ void gload16(const void* g, void* l) {
    __builtin_amdgcn_global_load_lds(
        (const __attribute__((address_space(1))) unsigned int*)g,
        (__attribute__((address_space(3))) unsigned int*)l, 16, 0, 0);
}

// ---------------- fp32 -> [hi|lo] bf16 split ----------------
__global__ __launch_bounds__(256)
void cvt_split(const float* __restrict__ A, __bf16* __restrict__ W) {
    const int idx = blockIdx.x * 256 + threadIdx.x;      // one float4 per thread
    const float4 v = reinterpret_cast<const float4*>(A)[idx];
    const int p = idx >> 6;                              // row (64 float4 / row)
    const int c = (idx & 63) * 4;
    float f[4] = {v.x, v.y, v.z, v.w};
    bf16x4 h, l;
#pragma unroll
    for (int i = 0; i < 4; ++i) {
        __bf16 hi = (__bf16)f[i];
        h[i] = hi;
        l[i] = (__bf16)(f[i] - (float)hi);
    }
    *reinterpret_cast<bf16x4*>(W + (size_t)p * KB + c) = h;
    *reinterpret_cast<bf16x4*>(W + (size_t)p * KB + 256 + c) = l;
}

// ---------------- MFMA main kernel ----------------
__device__ __forceinline__ int swz(int row) { return ((row >> 1) & 3) << 4; }

__global__ __launch_bounds__(256, 2)
void evd_mfma(const __bf16* __restrict__ W, float* __restrict__ out)
{
    const int bi = blockIdx.y, bk = blockIdx.x;
    if (bk < bi) return;                                  // upper triangle only

    __shared__ __bf16 As[BM * BK];                        // row pitch 32 bf16 = 64 B
    __shared__ __bf16 Bs[BM * BK];                        // content swizzled via source
    __shared__ float wsum[4];

    const int tid = threadIdx.x;
    const int lane = tid & 63, wid = tid >> 6;
    const int wr = wid >> 1, wc = wid & 1;                // 2x2 waves, 64x64 each
    const int row0 = bi * BM, col0 = bk * BM;

    f32x4 acc[4][4];
#pragma unroll
    for (int m = 0; m < 4; ++m)
#pragma unroll
        for (int n = 0; n < 4; ++n)
#pragma unroll
            for (int q = 0; q < 4; ++q) acc[m][n][q] = 0.f;

    // staging descriptors: issue s covers LDS bytes [s*4096 + tid*16, +16)
    // LDS off -> (row = off>>6, x = off&63); global col-byte = x ^ swz(row)
    const int r0 = tid >> 2;                              // rows 0..63   (s=0)
    const int r1 = 64 + r0;                               // rows 64..127 (s=1)
    const int x0 = (tid & 3) * 16;
    const int ga0 = r0 * (KB * 2) + (x0 ^ swz(r0));
    const int ga1 = r1 * (KB * 2) + (x0 ^ swz(r1));
    const char* gAb = (const char*)(W + (size_t)row0 * KB);
    const char* gBb = (const char*)(W + (size_t)col0 * KB);
    char* ldsA = (char*)As + wid * 1024;
    char* ldsB = (char*)Bs + wid * 1024;

    // frag read byte offsets (swizzled)
    const int fr = lane & 15, kb = (lane >> 4) * 16;
    int aoff[4], boff[4];
#pragma unroll
    for (int m = 0; m < 4; ++m) {
        const int ra = wr * 64 + m * 16 + fr;
        const int rb = wc * 64 + m * 16 + fr;
        aoff[m] = ra * 64 + (kb ^ swz(ra));
        boff[m] = rb * 64 + (kb ^ swz(rb));
    }

    for (int kc = 0; kc < KB; kc += BK) {
        const int kbyte = kc * 2;
        gload16(gAb + ga0 + kbyte, ldsA);
        gload16(gAb + ga1 + kbyte, ldsA + 4096);
        gload16(gBb + ga0 + kbyte, ldsB);
        gload16(gBb + ga1 + kbyte, ldsB + 4096);
        __syncthreads();

        bf16x8 af[4], bf[4];
#pragma unroll
        for (int m = 0; m < 4; ++m) {
            af[m] = *reinterpret_cast<const bf16x8*>((const char*)As + aoff[m]);
            bf[m] = *reinterpret_cast<const bf16x8*>((const char*)Bs + boff[m]);
        }
#pragma unroll
        for (int m = 0; m < 4; ++m)
#pragma unroll
            for (int n = 0; n < 4; ++n)
                acc[m][n] = __builtin_amdgcn_mfma_f32_16x16x32_bf16(af[m], bf[n], acc[m][n], 0, 0, 0);
        __syncthreads();
    }

    // ---------------- fused epilogue ----------------
    // C/D layout: col = lane&15, row = (lane>>4)*4 + reg
    const float C_NEG = 1.0f / (2048.0f * 2047.0f * 16.0f);
    const float C_POS = 2.0f / (2048.0f * 12.0f);
    const bool diag = (bi == bk);
    float contrib = 0.f;

#pragma unroll
    for (int m = 0; m < 4; ++m) {
#pragma unroll
        for (int n = 0; n < 4; ++n) {
            const bool dfrag = diag && (wr == wc) && (m == n);
            // row-side: i from rows, l-group = 4 adjacent lanes (bits 0,1 of lane)
#pragma unroll
            for (int r = 0; r < 4; ++r) {
                const float s = acc[m][n][r];
                const float m1 = fmaxf(s, __shfl_xor(s, 1));
                const float mm = fmaxf(m1, __shfl_xor(m1, 2));
                const float dp = __expf(s - mm);
                if (dfrag) {
                    const bool ik = ((lane >> 4) == ((lane & 15) >> 2));
                    if (ik) {
                        if (r != (lane & 3)) contrib -= C_POS * dp;   // j != l
                    } else {
                        contrib += C_NEG * fmaxf(dp * dp, 1e-8f);
                    }
                } else {
                    contrib += C_NEG * fmaxf(dp * dp, 1e-8f);
                }
            }
            // transposed side (off-diag tiles): l'-group = the 4 regs (4 consecutive rows)
            if (!diag) {
                const float mm2 = fmaxf(fmaxf(acc[m][n][0], acc[m][n][1]),
                                        fmaxf(acc[m][n][2], acc[m][n][3]));
#pragma unroll
                for (int r = 0; r < 4; ++r) {
                    const float dp = __expf(acc[m][n][r] - mm2);
                    contrib += C_NEG * fmaxf(dp * dp, 1e-8f);
                }
            }
        }
    }

    // block reduction -> one atomic per block
#pragma unroll
    for (int off = 32; off; off >>= 1) contrib += __shfl_down(contrib, off);
    if ((tid & 63) == 0) wsum[tid >> 6] = contrib;
    __syncthreads();
    if (tid == 0) atomicAdd(out, wsum[0] + wsum[1] + wsum[2] + wsum[3]);
}

// ---------------- fp32 fallback (round-1 kernel, known good) ----------------
#define KS  16
#define LDP 132

__device__ __forceinline__ float groupNeg(float s0, float s1, float s2, float s3) {
    float mmax = fmaxf(fmaxf(s0, s1), fmaxf(s2, s3));
    float d0 = __expf(s0 - mmax), d1 = __expf(s1 - mmax);
    float d2 = __expf(s2 - mmax), d3 = __expf(s3 - mmax);
    return fmaxf(d0 * d0, 1e-8f) + fmaxf(d1 * d1, 1e-8f) +
           fmaxf(d2 * d2, 1e-8f) + fmaxf(d3 * d3, 1e-8f);
}

__global__ __launch_bounds__(256, 2)
void evd_fp32(const float* __restrict__ A, float* __restrict__ out)
{
    const int bi = blockIdx.y, bk = blockIdx.x;
    if (bk < bi) return;
    __shared__ float As[KS][LDP];
    __shared__ float Bs[KS][LDP];
    __shared__ float wsum[4];
    const int tid = threadIdx.x;
    const int tx = tid & 15, ty = tid >> 4;
    const int row0 = bi * BM, col0 = bk * BM;
    float acc[8][8];
#pragma unroll
    for (int m = 0; m < 8; ++m)
#pragma unroll
        for (int n = 0; n < 8; ++n) acc[m][n] = 0.f;
    const float* __restrict__ Arow = A + (size_t)row0 * DDIM;
    const float* __restrict__ Brow = A + (size_t)col0 * DDIM;
    for (int kc = 0; kc < DDIM; kc += KS) {
#pragma unroll
        for (int u = 0; u < 2; ++u) {
            const int e = tid + u * 256;
            const int r = e >> 2, g = e & 3;
            const float4 va = *reinterpret_cast<const float4*>(Arow + r * DDIM + kc + g * 4);
            As[g * 4 + 0][r] = va.x; As[g * 4 + 1][r] = va.y;
            As[g * 4 + 2][r] = va.z; As[g * 4 + 3][r] = va.w;
            const float4 vb = *reinterpret_cast<const float4*>(Brow + r * DDIM + kc + g * 4);
            Bs[g * 4 + 0][r] = vb.x; Bs[g * 4 + 1][r] = vb.y;
            Bs[g * 4 + 2][r] = vb.z; Bs[g * 4 + 3][r] = vb.w;
        }
        __syncthreads();
#pragma unroll
        for (int kk = 0; kk < KS; ++kk) {
            float a[8], b[8];
            *(float4*)&a[0] = *(const float4*)&As[kk][ty * 8];
            *(float4*)&a[4] = *(const float4*)&As[kk][ty * 8 + 4];
            *(float4*)&b[0] = *(const float4*)&Bs[kk][tx * 8];
            *(float4*)&b[4] = *(const float4*)&Bs[kk][tx * 8 + 4];
#pragma unroll
            for (int m = 0; m < 8; ++m)
#pragma unroll
                for (int n = 0; n < 8; ++n)
                    acc[m][n] = fmaf(a[m], b[n], acc[m][n]);
        }
        __syncthreads();
    }
    const float C_NEG = 1.0f / (2048.0f * 2047.0f * 16.0f);
    const float C_POS = 2.0f / (2048.0f * 12.0f);
    float contrib = 0.f;
#pragma unroll
    for (int m = 0; m < 8; ++m) {
        const int p = row0 + ty * 8 + m;
        const int i = p >> 2, j = p & 3;
#pragma unroll
        for (int kg = 0; kg < 2; ++kg) {
            const int k = (col0 + tx * 8 + kg * 4) >> 2;
            const float s0 = acc[m][kg * 4 + 0], s1 = acc[m][kg * 4 + 1];
            const float s2 = acc[m][kg * 4 + 2], s3 = acc[m][kg * 4 + 3];
            if (i != k) {
                contrib += C_NEG * groupNeg(s0, s1, s2, s3);
            } else {
                const float mmax = fmaxf(fmaxf(s0, s1), fmaxf(s2, s3));
                const float d0 = __expf(s0 - mmax), d1 = __expf(s1 - mmax);
                const float d2 = __expf(s2 - mmax), d3 = __expf(s3 - mmax);
                const float dj = (j == 0) ? d0 : (j == 1) ? d1 : (j == 2) ? d2 : d3;
                contrib -= C_POS * (d0 + d1 + d2 + d3 - dj);
            }
        }
    }
    if (bi != bk) {
#pragma unroll
        for (int n = 0; n < 8; ++n)
#pragma unroll
            for (int mg = 0; mg < 2; ++mg)
                contrib += C_NEG * groupNeg(acc[mg * 4 + 0][n], acc[mg * 4 + 1][n],
                                            acc[mg * 4 + 2][n], acc[mg * 4 + 3][n]);
    }
#pragma unroll
    for (int off = 32; off; off >>= 1) contrib += __shfl_down(contrib, off);
    if ((tid & 63) == 0) wsum[tid >> 6] = contrib;
    __syncthreads();
    if (tid == 0) atomicAdd(out, wsum[0] + wsum[1] + wsum[2] + wsum[3]);
}

extern "C" void kernel_launch(void* const* d_in, const int* in_sizes, int n_in,
                              void* d_out, int out_size, void* d_ws, size_t ws_size,
                              hipStream_t stream) {
    const float* A = (const float*)d_in[0];
    float* out = (float*)d_out;
    hipMemsetAsync(out, 0, sizeof(float), stream);

    const size_t need = (size_t)PD * KB * sizeof(__bf16);   // 8 MB
    if (ws_size >= need) {
        __bf16* W = (__bf16*)d_ws;
        cvt_split<<<(PD * DDIM / 4) / 256, 256, 0, stream>>>(A, W);
        dim3 grid(PD / BM, PD / BM);
        evd_mfma<<<grid, 256, 0, stream>>>(W, out);
    } else {
        dim3 grid(PD / BM, PD / BM);
        evd_fp32<<<grid, 256, 0, stream>>>(A, out);
    }
}